// Round 7
// baseline (312.531 us; speedup 1.0000x reference)
//
#include <hip/hip_runtime.h>

#define BB 16      // batch
#define SS 48      // seq len
#define VV 16000   // vocab
#define DD 128     // embed
#define NC (DD / 4)        // 32 float4 chunks per row — ALL loops derive from this
#define TV 64              // vocab rows per tile (lane = row)
#define TCH (TV * NC)      // 2048 chunks = 32 KB per tile
#define NTHREADS 128       // 2 waves: wave0 -> batches 0-7, wave1 -> 8-15
#define TPB 5              // tiles per block
#define BPS (VV / TV / TPB)   // 50 blocks per s  (50*5*64 = 16000 exactly)

constexpr float EPS   = 1e-8f;
constexpr float SCALE = 10.0f;

// Kernel 1 (unchanged, verified R2-R6): per-batch causal prefix context,
// normalized. One block = one batch, 64 threads. ctx_n layout [S][B][D].
__global__ __launch_bounds__(64) void ctx_kernel(
    const int*   __restrict__ tokens,   // [B,S]
    const float* __restrict__ scalars,  // [S,V]
    const float* __restrict__ wvecs,    // [S,V,D]
    float*       __restrict__ ctx_n)    // [S,B,D]
{
    const int b    = blockIdx.x;
    const int lane = threadIdx.x;  // 0..63

    float a[SS], w0[SS], w1[SS];
    #pragma unroll
    for (int s = 0; s < SS; ++s) {
        const int tok = tokens[b * SS + s];
        a[s] = scalars[(size_t)s * VV + tok];
        const float* wp = wvecs + ((size_t)s * VV + tok) * DD;
        w0[s] = wp[lane];
        w1[s] = wp[lane + 64];
    }

    float run0 = 0.f, run1 = 0.f;
    #pragma unroll
    for (int s = 0; s < SS; ++s) {
        float p = fmaf(run0, run0, run1 * run1);
        #pragma unroll
        for (int off = 32; off > 0; off >>= 1)
            p += __shfl_xor(p, off);
        const float denom = fmaxf(sqrtf(p), EPS);  // torch F.normalize semantics
        float* o = ctx_n + ((size_t)s * BB + b) * DD;
        o[lane]      = run0 / denom;
        o[lane + 64] = run1 / denom;
        run0 = fmaf(a[s], w0[s], run0);   // position s contributes to positions > s
        run1 = fmaf(a[s], w1[s], run1);
    }
}

// swizzled LDS chunk index: row r = gi>>5, col c = gi&31 -> r*32 + (c ^ (r&7)).
// Applied identically on ds_write and ds_read (both-sides swizzle, T2).
__device__ __forceinline__ int swz(int gi) {
    return (gi & ~31) | ((gi & 31) ^ ((gi >> 5) & 7));
}

// Kernel 2: out[b,s,v] = SCALE * dot(ctx_n[b,s,:], emb[s,v,:]) / max(||emb[s,v,:]||, eps)
//
// R6 post-mortem: 16-lane-broadcast LDS reads delivered only 64 distinct
// bytes per ds_read_b128 -> ~120us of LDS-pipe serialization. Redesign:
//   - lane = row: each ds_read_b128 carries 1KB distinct data (XOR-swizzled
//     to kill the stride-512B 32-way bank conflict).
//   - ctx operands come from uniform scalar-path loads (no threadIdx in the
//     address), never touching LDS.
//   - async double-buffer: issue next tile's 16 coalesced dwordx4 into regs
//     BEFORE computing current tile; ds_write after barrier (T14).
__global__ __launch_bounds__(NTHREADS) void logits_kernel(
    const float* __restrict__ ctx_n,  // [S,B,D] (normalized)
    const float* __restrict__ emb,    // [S,V,D]
    float*       __restrict__ out)    // [B,S,V]
{
    const int s     = blockIdx.y;
    const int tile0 = blockIdx.x * TPB;
    const int tid   = threadIdx.x;       // 0..127
    const int lane  = tid & 63;          // row within tile
    const int wu    = __builtin_amdgcn_readfirstlane(tid >> 6);  // wave id, provably uniform
    const int rx    = lane & 7;          // read-swizzle key for this lane's row

    __shared__ float4 tileA[TCH];        // 32 KB

    const float4* ebase = (const float4*)emb   + (size_t)s * VV * NC;
    const float4* cbase = (const float4*)ctx_n + (size_t)s * BB * NC
                        + (size_t)(wu * 8) * NC;   // this wave's 8 batches

    float4 G[16];

    // Prologue: stage tile0.
    {
        const float4* tsrc = ebase + (size_t)tile0 * TCH;
        #pragma unroll
        for (int k = 0; k < 16; ++k) G[k] = tsrc[tid + k * NTHREADS];
        #pragma unroll
        for (int k = 0; k < 16; ++k) tileA[swz(tid + k * NTHREADS)] = G[k];
    }
    __syncthreads();

    for (int ti = 0; ti < TPB; ++ti) {
        // Issue next tile's coalesced loads first: HBM latency hides under compute.
        if (ti + 1 < TPB) {
            const float4* tsrc = ebase + (size_t)(tile0 + ti + 1) * TCH;
            #pragma unroll
            for (int k = 0; k < 16; ++k) G[k] = tsrc[tid + k * NTHREADS];
        }

        // Compute current tile: lane owns row `lane`; full-BW swizzled LDS reads.
        float acc[8];
        #pragma unroll
        for (int bb = 0; bb < 8; ++bb) acc[bb] = 0.f;
        float pn = 0.f;

        const int rbase = lane * NC;
        #pragma unroll 8
        for (int j = 0; j < NC; ++j) {
            const float4 e = tileA[rbase + (j ^ rx)];
            pn = fmaf(e.x, e.x, pn);
            pn = fmaf(e.y, e.y, pn);
            pn = fmaf(e.z, e.z, pn);
            pn = fmaf(e.w, e.w, pn);
            #pragma unroll
            for (int bb = 0; bb < 8; ++bb) {
                const float4 c = cbase[bb * NC + j];   // uniform -> scalar path
                acc[bb] = fmaf(e.x, c.x, acc[bb]);
                acc[bb] = fmaf(e.y, c.y, acc[bb]);
                acc[bb] = fmaf(e.z, c.z, acc[bb]);
                acc[bb] = fmaf(e.w, c.w, acc[bb]);
            }
        }

        // Epilogue for this tile: coalesced stores (lane-consecutive v).
        const int v = (tile0 + ti) * TV + lane;
        const float f = SCALE / fmaxf(sqrtf(pn), EPS);  // F.normalize semantics
        #pragma unroll
        for (int bb = 0; bb < 8; ++bb) {
            const int b = wu * 8 + bb;
            out[((size_t)b * SS + s) * VV + v] = acc[bb] * f;
        }

        // Publish the prefetched tile.
        if (ti + 1 < TPB) {
            __syncthreads();   // everyone done reading tileA
            #pragma unroll
            for (int k = 0; k < 16; ++k) tileA[swz(tid + k * NTHREADS)] = G[k];
            __syncthreads();   // writes visible to both waves
        }
    }
}

extern "C" void kernel_launch(void* const* d_in, const int* in_sizes, int n_in,
                              void* d_out, int out_size, void* d_ws, size_t ws_size,
                              hipStream_t stream) {
    const int*   tokens  = (const int*)d_in[0];
    const float* scalars = (const float*)d_in[1];
    const float* wvecs   = (const float*)d_in[2];
    const float* emb     = (const float*)d_in[3];
    float*       out     = (float*)d_out;
    float*       ctx_n   = (float*)d_ws;   // S*B*D*4 = 393,216 bytes

    ctx_kernel<<<dim3(BB), dim3(64), 0, stream>>>(tokens, scalars, wvecs, ctx_n);

    dim3 grid(BPS, SS);   // (50, 48) = 2400 blocks, 128 threads each
    logits_kernel<<<grid, dim3(NTHREADS), 0, stream>>>(ctx_n, emb, out);
}